// Round 4
// baseline (1822.013 us; speedup 1.0000x reference)
//
#include <hip/hip_runtime.h>

// GCN 3->32->32->1, N=100K, E=6.4M (+self loops).
// R3 lesson: random 4B global writes/atomics cost a 32B-sector line-op each
// (~11G/s device-wide) -> k_scatter 570us. R4: bucket counting-sort + LDS
// privatization. Nodes -> 782 buckets of 128. Histogram/scan/scatter give a
// dst-bucketed packed edge array (src | ldst<<17) with NO global atomics and
// sequential-run writes. Aggregations: one bucket per block, LDS accumulator
// (ds_add_f32), fused node math (W1/relu, W2/relu/W3-dot) in-block.
// norm factored: y = dis*x, g = dis*h1, q = dis*p; self-loop added in-block.

#define BLK 256
#define SB 1024          // scatter blocks / chunk count
#define BKT 128          // nodes per bucket
#define MAXNB 1024       // >= NB = ceil(N/BKT) = 782

// ---- pass 1: per-chunk histogram over dst buckets (LDS, no global atomics)
__global__ void k_hist(const int* __restrict__ dst, int* __restrict__ hist,
                       int E, int chunk, int NB) {
    __shared__ int lh[MAXNB];
    for (int b = threadIdx.x; b < NB; b += blockDim.x) lh[b] = 0;
    __syncthreads();
    int beg = blockIdx.x * chunk, end = min(E, beg + chunk);
    for (int e = beg + threadIdx.x; e < end; e += blockDim.x)
        atomicAdd(&lh[dst[e] >> 7], 1);
    __syncthreads();
    for (int b = threadIdx.x; b < NB; b += blockDim.x)
        hist[(size_t)blockIdx.x * NB + b] = lh[b];   // coalesced row write
}

// ---- scan A: per bucket, exclusive-scan its SB chunk-counts (in-place), total out
__global__ void k_scanA(int* __restrict__ hist, int* __restrict__ btot, int NB) {
    __shared__ int sh[SB];
    int b = blockIdx.x, t = threadIdx.x;
    int v = hist[(size_t)t * NB + b];
    sh[t] = v;
    __syncthreads();
    for (int off = 1; off < SB; off <<= 1) {
        int u = (t >= off) ? sh[t - off] : 0;
        __syncthreads();
        sh[t] += u;
        __syncthreads();
    }
    hist[(size_t)t * NB + b] = sh[t] - v;            // exclusive within bucket
    if (t == SB - 1) btot[b] = sh[t];
}

// ---- scan B: exclusive-scan bucket totals -> bucket base offsets
__global__ void k_scanB(const int* __restrict__ btot, int* __restrict__ bbase,
                        int NB, int E) {
    __shared__ int sh[MAXNB];
    int t = threadIdx.x;
    int v = (t < NB) ? btot[t] : 0;
    sh[t] = v;
    __syncthreads();
    for (int off = 1; off < MAXNB; off <<= 1) {
        int u = (t >= off) ? sh[t - off] : 0;
        __syncthreads();
        sh[t] += u;
        __syncthreads();
    }
    if (t < NB) bbase[t] = sh[t] - v;
    if (t == 0) bbase[NB] = E;
}

// ---- pass 2: scatter into bucket regions, LDS cursors (no global atomics)
__global__ void k_scat(const int* __restrict__ src, const int* __restrict__ dst,
                       const int* __restrict__ hist, const int* __restrict__ bbase,
                       unsigned int* __restrict__ packed, int E, int chunk, int NB) {
    __shared__ int base[MAXNB];
    __shared__ int cur[MAXNB];
    for (int b = threadIdx.x; b < NB; b += blockDim.x) {
        base[b] = bbase[b] + hist[(size_t)blockIdx.x * NB + b];
        cur[b] = 0;
    }
    __syncthreads();
    int beg = blockIdx.x * chunk, end = min(E, beg + chunk);
    for (int e = beg + threadIdx.x; e < end; e += blockDim.x) {
        int d = dst[e];
        int b = d >> 7;
        int off = atomicAdd(&cur[b], 1);             // LDS atomic
        packed[base[b] + off] = (unsigned)src[e] | ((unsigned)(d & 127) << 17);
    }
}

// ---- in-degree from packed edges (LDS count) -> dis, y4 = dis*x
__global__ void k_prep(const unsigned int* __restrict__ packed, const int* __restrict__ bbase,
                       const float* __restrict__ x, float* __restrict__ dis,
                       float4* __restrict__ y4, int N) {
    __shared__ int cnt[BKT];
    if (threadIdx.x < BKT) cnt[threadIdx.x] = 0;
    __syncthreads();
    int b = blockIdx.x;
    int beg = bbase[b], end = bbase[b + 1];
    for (int e = beg + threadIdx.x; e < end; e += blockDim.x)
        atomicAdd(&cnt[packed[e] >> 17], 1);
    __syncthreads();
    if (threadIdx.x < BKT) {
        int gi = b * BKT + threadIdx.x;
        if (gi < N) {
            float di = rsqrtf((float)cnt[threadIdx.x] + 1.0f);  // + self loop
            dis[gi] = di;
            float4 y;
            y.x = di * x[3 * gi + 0];
            y.y = di * x[3 * gi + 1];
            y.z = di * x[3 * gi + 2];
            y.w = 0.0f;
            y4[gi] = y;
        }
    }
}

// ---- layer 1: LDS-accumulate y4[src] per local dst, then fused W1+relu, g=dis*h1
__global__ void k_l1(const unsigned int* __restrict__ packed, const int* __restrict__ bbase,
                     const float4* __restrict__ y4, const float* __restrict__ dis,
                     const float* __restrict__ W1, const float* __restrict__ b1,
                     float* __restrict__ g, int N) {
    __shared__ float acc[BKT * 4];
    for (int i = threadIdx.x; i < BKT * 4; i += blockDim.x) acc[i] = 0.f;
    __syncthreads();
    int b = blockIdx.x;
    int beg = bbase[b], end = bbase[b + 1];
    for (int e = beg + threadIdx.x; e < end; e += blockDim.x) {
        unsigned v = packed[e];
        int s = v & 0x1FFFF, l = v >> 17;
        float4 y = y4[s];                            // 16B gather, y4 L2-resident
        atomicAdd(&acc[l * 4 + 0], y.x);
        atomicAdd(&acc[l * 4 + 1], y.y);
        atomicAdd(&acc[l * 4 + 2], y.z);
    }
    __syncthreads();
    int j = threadIdx.x & 31;
    for (int n = threadIdx.x >> 5; n < BKT; n += blockDim.x >> 5) {
        int gi = b * BKT + n;
        if (gi >= N) break;
        float di = dis[gi];
        float4 ys = y4[gi];                          // self loop
        float a0 = di * (acc[n * 4 + 0] + ys.x);
        float a1 = di * (acc[n * 4 + 1] + ys.y);
        float a2 = di * (acc[n * 4 + 2] + ys.z);
        float h = b1[j] + a0 * W1[j] + a1 * W1[32 + j] + a2 * W1[64 + j];
        g[(size_t)gi * 32 + j] = di * fmaxf(h, 0.f);
    }
}

// ---- layer 2 (+L3 projection): 32 lanes/edge LDS-accumulate g rows, fused W2/relu/W3
__global__ void k_l2(const unsigned int* __restrict__ packed, const int* __restrict__ bbase,
                     const float* __restrict__ g, const float* __restrict__ dis,
                     const float* __restrict__ W2, const float* __restrict__ b2,
                     const float* __restrict__ W3, float* __restrict__ q, int N) {
    __shared__ float acc[BKT * 32];                  // 16 KB
    for (int i = threadIdx.x; i < BKT * 32; i += blockDim.x) acc[i] = 0.f;
    __syncthreads();
    int b = blockIdx.x;
    int beg = bbase[b], end = bbase[b + 1];
    int j = threadIdx.x & 31;
    int slot = threadIdx.x >> 5;                     // 0..7 (8 edge-groups/block)
    for (int e = beg + slot; e < end; e += 8) {
        unsigned v = packed[e];                      // broadcast (uniform in group)
        int s = v & 0x1FFFF, l = v >> 17;
        atomicAdd(&acc[l * 32 + j], g[(size_t)s * 32 + j]);   // 128B row gather
    }
    __syncthreads();
    for (int n = threadIdx.x >> 5; n < BKT; n += 8) {
        int gi = b * BKT + n;
        if (gi >= N) break;
        float di = dis[gi];
        float a = di * (acc[n * 32 + j] + g[(size_t)gi * 32 + j]);  // + self loop
        float o = b2[j];
#pragma unroll
        for (int k = 0; k < 32; k++)
            o += __shfl(a, k, 32) * W2[k * 32 + j];
        float h2 = fmaxf(o, 0.f);
        float c = h2 * W3[j];
#pragma unroll
        for (int m = 16; m >= 1; m >>= 1)
            c += __shfl_xor(c, m, 32);
        if (j == 0) q[gi] = di * c;                  // q = dis * p
    }
}

// ---- layer 3: scalar q gathers into LDS acc, fused output
__global__ void k_l3(const unsigned int* __restrict__ packed, const int* __restrict__ bbase,
                     const float* __restrict__ q, const float* __restrict__ dis,
                     const float* __restrict__ b3, float* __restrict__ out, int N) {
    __shared__ float acc[BKT];
    if (threadIdx.x < BKT) acc[threadIdx.x] = 0.f;
    __syncthreads();
    int b = blockIdx.x;
    int beg = bbase[b], end = bbase[b + 1];
    for (int e = beg + threadIdx.x; e < end; e += blockDim.x) {
        unsigned v = packed[e];
        atomicAdd(&acc[v >> 17], q[v & 0x1FFFF]);    // q is 400KB, L2-resident
    }
    __syncthreads();
    if (threadIdx.x < BKT) {
        int gi = b * BKT + threadIdx.x;
        if (gi < N) out[gi] = dis[gi] * (acc[threadIdx.x] + q[gi]) + b3[0];
    }
}

extern "C" void kernel_launch(void* const* d_in, const int* in_sizes, int n_in,
                              void* d_out, int out_size, void* d_ws, size_t ws_size,
                              hipStream_t stream) {
    const float* x  = (const float*)d_in[0];
    const int*   ei = (const int*)d_in[1];
    const float* W1 = (const float*)d_in[2];
    const float* b1 = (const float*)d_in[3];
    const float* W2 = (const float*)d_in[4];
    const float* b2 = (const float*)d_in[5];
    const float* W3 = (const float*)d_in[6];
    const float* b3 = (const float*)d_in[7];
    float* out = (float*)d_out;

    int N = in_sizes[0] / 3;
    int E = in_sizes[1] / 2;
    const int* src = ei;
    const int* dst = ei + E;
    int NB = (N + BKT - 1) / BKT;                    // 782
    int chunk = (E + SB - 1) / SB;

    // workspace (all init done in-kernel; no memset needed)
    char* w = (char*)d_ws;
    int*   hist   = (int*)w;       w += (size_t)SB * NB * 4;   // 3.2 MB
    int*   btot   = (int*)w;       w += (size_t)MAXNB * 4;
    int*   bbase  = (int*)w;       w += (size_t)(MAXNB + 1) * 4;
    float* dis    = (float*)w;     w += (size_t)N * 4;
    float* y4     = (float*)w;     w += (size_t)N * 16;
    float* g      = (float*)w;     w += (size_t)N * 32 * 4;     // 12.8 MB
    float* q      = (float*)w;     w += (size_t)N * 4;
    unsigned int* packed = (unsigned int*)w;  w += (size_t)E * 4;  // 25.6 MB

    k_hist <<<SB, BLK, 0, stream>>>(dst, hist, E, chunk, NB);
    k_scanA<<<NB, SB, 0, stream>>>(hist, btot, NB);
    k_scanB<<<1, MAXNB, 0, stream>>>(btot, bbase, NB, E);
    k_scat <<<SB, BLK, 0, stream>>>(src, dst, hist, bbase, packed, E, chunk, NB);

    k_prep <<<NB, BLK, 0, stream>>>(packed, bbase, x, dis, (float4*)y4, N);
    k_l1   <<<NB, BLK, 0, stream>>>(packed, bbase, (const float4*)y4, dis, W1, b1, g, N);
    k_l2   <<<NB, BLK, 0, stream>>>(packed, bbase, g, dis, W2, b2, W3, q, N);
    k_l3   <<<NB, BLK, 0, stream>>>(packed, bbase, q, dis, b3, out, N);
}

// Round 5
// 543.373 us; speedup vs baseline: 3.3532x; 3.3532x over previous
//
#include <hip/hip_runtime.h>

// GCN 3->32->32->1, N=100K, E=6.4M (+self loops).
// R4 lesson: bucket-local aggregation starved MLP (6K gather streams, occ 24%,
// 1404us). R5: keep the atomic-free bucket sort, extend it to a full per-node
// CSR (k_prep scans per-node counts -> rowptr; k_scat2 sorts each bucket
// in-place through LDS). Aggregate node-parallel (R3 style, 100K independent
// 32-lane streams). Zero global atomics anywhere.
// norm factored: y = dis*x, g = dis*h1, q = dis*p; self-loop added per node.

#define BLK 256
#define SB 1024          // first-pass chunks
#define BKT 128          // nodes per bucket
#define MAXNB 1024       // >= NB = ceil(N/BKT) = 782
#define BUFSZ 15360      // in-place sort LDS buffer (mean bucket 8192, 79 sigma)

// ---- pass 1: per-chunk histogram over dst buckets (LDS, no global atomics)
__global__ void k_hist(const int* __restrict__ dst, int* __restrict__ hist,
                       int E, int chunk, int NB) {
    __shared__ int lh[MAXNB];
    for (int b = threadIdx.x; b < NB; b += blockDim.x) lh[b] = 0;
    __syncthreads();
    int beg = blockIdx.x * chunk, end = min(E, beg + chunk);
    for (int e = beg + threadIdx.x; e < end; e += blockDim.x)
        atomicAdd(&lh[dst[e] >> 7], 1);
    __syncthreads();
    for (int b = threadIdx.x; b < NB; b += blockDim.x)
        hist[(size_t)blockIdx.x * NB + b] = lh[b];
}

// ---- scan A: per bucket, exclusive-scan its SB chunk-counts, total out
__global__ void k_scanA(int* __restrict__ hist, int* __restrict__ btot, int NB) {
    __shared__ int sh[SB];
    int b = blockIdx.x, t = threadIdx.x;
    int v = hist[(size_t)t * NB + b];
    sh[t] = v;
    __syncthreads();
    for (int off = 1; off < SB; off <<= 1) {
        int u = (t >= off) ? sh[t - off] : 0;
        __syncthreads();
        sh[t] += u;
        __syncthreads();
    }
    hist[(size_t)t * NB + b] = sh[t] - v;
    if (t == SB - 1) btot[b] = sh[t];
}

// ---- scan B: exclusive-scan bucket totals -> bucket base offsets
__global__ void k_scanB(const int* __restrict__ btot, int* __restrict__ bbase,
                        int NB, int E) {
    __shared__ int sh[MAXNB];
    int t = threadIdx.x;
    int v = (t < NB) ? btot[t] : 0;
    sh[t] = v;
    __syncthreads();
    for (int off = 1; off < MAXNB; off <<= 1) {
        int u = (t >= off) ? sh[t - off] : 0;
        __syncthreads();
        sh[t] += u;
        __syncthreads();
    }
    if (t < NB) bbase[t] = sh[t] - v;
    if (t == 0) bbase[NB] = E;
}

// ---- pass 2: scatter into bucket regions, LDS cursors (no global atomics)
__global__ void k_scat(const int* __restrict__ src, const int* __restrict__ dst,
                       const int* __restrict__ hist, const int* __restrict__ bbase,
                       unsigned int* __restrict__ packed, int E, int chunk, int NB) {
    __shared__ int base[MAXNB];
    __shared__ int cur[MAXNB];
    for (int b = threadIdx.x; b < NB; b += blockDim.x) {
        base[b] = bbase[b] + hist[(size_t)blockIdx.x * NB + b];
        cur[b] = 0;
    }
    __syncthreads();
    int beg = blockIdx.x * chunk, end = min(E, beg + chunk);
    for (int e = beg + threadIdx.x; e < end; e += blockDim.x) {
        int d = dst[e];
        int b = d >> 7;
        int off = atomicAdd(&cur[b], 1);
        packed[base[b] + off] = (unsigned)src[e] | ((unsigned)(d & 127) << 17);
    }
}

// ---- per-node degree -> dis, y4 = dis*x, rowptr (bucket base + local scan)
__global__ void k_prep(const unsigned int* __restrict__ packed, const int* __restrict__ bbase,
                       const float* __restrict__ x, float* __restrict__ dis,
                       float4* __restrict__ y4, int* __restrict__ rowptr, int N, int E) {
    __shared__ int cnt[BKT];
    __shared__ int sc[BKT];
    int t = threadIdx.x;
    if (t < BKT) cnt[t] = 0;
    __syncthreads();
    int b = blockIdx.x;
    int beg = bbase[b], end = bbase[b + 1];
    for (int e = beg + t; e < end; e += blockDim.x)
        atomicAdd(&cnt[packed[e] >> 17], 1);
    __syncthreads();
    int v = 0;
    if (t < BKT) { v = cnt[t]; sc[t] = v; }
    __syncthreads();
    for (int off = 1; off < BKT; off <<= 1) {
        int u = 0;
        if (t < BKT && t >= off) u = sc[t - off];
        __syncthreads();
        if (t < BKT) sc[t] += u;
        __syncthreads();
    }
    if (t < BKT) {
        int gi = b * BKT + t;
        if (gi < N) {
            rowptr[gi] = beg + sc[t] - v;            // exclusive
            float di = rsqrtf((float)v + 1.0f);      // + self loop
            dis[gi] = di;
            float4 y;
            y.x = di * x[3 * gi + 0];
            y.y = di * x[3 * gi + 1];
            y.z = di * x[3 * gi + 2];
            y.w = 0.0f;
            y4[gi] = y;
        }
    }
    if (b == 0 && t == 0) rowptr[N] = E;
}

// ---- within-bucket counting sort, in place via LDS (packed -> per-node csr)
__global__ void k_scat2(unsigned int* __restrict__ packed, const int* __restrict__ bbase,
                        const int* __restrict__ rowptr, int N) {
    __shared__ unsigned int buf[BUFSZ];
    __shared__ int cur[BKT];
    int b = blockIdx.x;
    int beg = bbase[b], end = bbase[b + 1];
    int len = end - beg;
    for (int i = threadIdx.x; i < len; i += blockDim.x) buf[i] = packed[beg + i];
    if (threadIdx.x < BKT) {
        int gi = b * BKT + threadIdx.x;
        cur[threadIdx.x] = (gi < N) ? rowptr[gi] : 0;
    }
    __syncthreads();
    for (int i = threadIdx.x; i < len; i += blockDim.x) {
        unsigned v = buf[i];
        int pos = atomicAdd(&cur[v >> 17], 1);       // LDS atomic
        packed[pos] = v & 0x1FFFF;                   // now plain src id
    }
}

// ---- layer 1: node-parallel, 32 lanes/node gather y4 (L2-resident 1.6MB)
__global__ void k_l1(const unsigned int* __restrict__ csr, const int* __restrict__ rowptr,
                     const float4* __restrict__ y4, const float* __restrict__ dis,
                     const float* __restrict__ W1, const float* __restrict__ b1,
                     float* __restrict__ g, int N) {
    int t = blockIdx.x * blockDim.x + threadIdx.x;
    int i = t >> 5, j = t & 31;
    if (i >= N) return;
    int beg = rowptr[i], end = rowptr[i + 1];
    float ax = 0.f, ay = 0.f, az = 0.f;
    for (int e = beg + j; e < end; e += 32) {
        float4 yv = y4[csr[e]];
        ax += yv.x; ay += yv.y; az += yv.z;
    }
#pragma unroll
    for (int m = 16; m >= 1; m >>= 1) {
        ax += __shfl_xor(ax, m, 32);
        ay += __shfl_xor(ay, m, 32);
        az += __shfl_xor(az, m, 32);
    }
    float di = dis[i];
    float4 ys = y4[i];                               // self loop (pre-scaled)
    float a0 = di * (ax + ys.x);
    float a1 = di * (ay + ys.y);
    float a2 = di * (az + ys.z);
    float h = b1[j] + a0 * W1[j] + a1 * W1[32 + j] + a2 * W1[64 + j];
    g[(size_t)i * 32 + j] = di * fmaxf(h, 0.f);
}

// ---- layer 2 (+L3 projection): node-parallel, broadcast edge ids, 128B row gathers
__global__ void k_l2(const unsigned int* __restrict__ csr, const int* __restrict__ rowptr,
                     const float* __restrict__ g, const float* __restrict__ dis,
                     const float* __restrict__ W2, const float* __restrict__ b2,
                     const float* __restrict__ W3, float* __restrict__ q, int N) {
    int t = blockIdx.x * blockDim.x + threadIdx.x;
    int i = t >> 5, j = t & 31;
    if (i >= N) return;
    int beg = rowptr[i], end = rowptr[i + 1];
    float acc = 0.f;
    for (int k0 = beg; k0 < end; k0 += 32) {
        int e = k0 + j;
        int myedge = (e < end) ? (int)csr[e] : 0;    // coalesced chunk load
        int cnt = min(32, end - k0);
        for (int t2 = 0; t2 < cnt; t2++) {
            int s = __shfl(myedge, t2, 32);          // broadcast edge id
            acc += g[(size_t)s * 32 + j];            // 128B coalesced row
        }
    }
    float di = dis[i];
    float a = di * (acc + g[(size_t)i * 32 + j]);    // + self loop
    float o = b2[j];
#pragma unroll
    for (int k = 0; k < 32; k++)
        o += __shfl(a, k, 32) * W2[k * 32 + j];
    float h2 = fmaxf(o, 0.f);
    float c = h2 * W3[j];
#pragma unroll
    for (int m = 16; m >= 1; m >>= 1)
        c += __shfl_xor(c, m, 32);
    if (j == 0) q[i] = di * c;                       // q = dis * p
}

// ---- layer 3: node-parallel scalar q gathers (q 400KB, L2-resident)
__global__ void k_l3(const unsigned int* __restrict__ csr, const int* __restrict__ rowptr,
                     const float* __restrict__ q, const float* __restrict__ dis,
                     const float* __restrict__ b3, float* __restrict__ out, int N) {
    int t = blockIdx.x * blockDim.x + threadIdx.x;
    int i = t >> 5, j = t & 31;
    if (i >= N) return;
    int beg = rowptr[i], end = rowptr[i + 1];
    float acc = 0.f;
    for (int e = beg + j; e < end; e += 32)
        acc += q[csr[e]];
#pragma unroll
    for (int m = 16; m >= 1; m >>= 1)
        acc += __shfl_xor(acc, m, 32);
    if (j == 0) out[i] = dis[i] * (acc + q[i]) + b3[0];
}

extern "C" void kernel_launch(void* const* d_in, const int* in_sizes, int n_in,
                              void* d_out, int out_size, void* d_ws, size_t ws_size,
                              hipStream_t stream) {
    const float* x  = (const float*)d_in[0];
    const int*   ei = (const int*)d_in[1];
    const float* W1 = (const float*)d_in[2];
    const float* b1 = (const float*)d_in[3];
    const float* W2 = (const float*)d_in[4];
    const float* b2 = (const float*)d_in[5];
    const float* W3 = (const float*)d_in[6];
    const float* b3 = (const float*)d_in[7];
    float* out = (float*)d_out;

    int N = in_sizes[0] / 3;
    int E = in_sizes[1] / 2;
    const int* src = ei;
    const int* dst = ei + E;
    int NB = (N + BKT - 1) / BKT;                    // 782
    int chunk = (E + SB - 1) / SB;

    // workspace (all init done in-kernel; no memset needed)
    char* w = (char*)d_ws;
    int*   hist   = (int*)w;       w += (size_t)SB * NB * 4;        // 3.2 MB
    int*   btot   = (int*)w;       w += (size_t)MAXNB * 4;
    int*   bbase  = (int*)w;       w += (size_t)(MAXNB + 1) * 4;
    int*   rowptr = (int*)w;       w += (size_t)(N + 1) * 4;
    float* dis    = (float*)w;     w += (size_t)N * 4;
    float* y4     = (float*)w;     w += (size_t)N * 16;
    float* g      = (float*)w;     w += (size_t)N * 32 * 4;          // 12.8 MB
    float* q      = (float*)w;     w += (size_t)N * 4;
    unsigned int* packed = (unsigned int*)w;  w += (size_t)E * 4;    // 25.6 MB

    k_hist <<<SB, BLK, 0, stream>>>(dst, hist, E, chunk, NB);
    k_scanA<<<NB, SB, 0, stream>>>(hist, btot, NB);
    k_scanB<<<1, MAXNB, 0, stream>>>(btot, bbase, NB, E);
    k_scat <<<SB, BLK, 0, stream>>>(src, dst, hist, bbase, packed, E, chunk, NB);
    k_prep <<<NB, BLK, 0, stream>>>(packed, bbase, x, dis, (float4*)y4, rowptr, N, E);
    k_scat2<<<NB, BLK, 0, stream>>>(packed, bbase, rowptr, N);

    long long tn = (long long)N * 32;
    unsigned gn = (unsigned)((tn + BLK - 1) / BLK);
    k_l1<<<gn, BLK, 0, stream>>>(packed, rowptr, (const float4*)y4, dis, W1, b1, g, N);
    k_l2<<<gn, BLK, 0, stream>>>(packed, rowptr, g, dis, W2, b2, W3, q, N);
    k_l3<<<gn, BLK, 0, stream>>>(packed, rowptr, q, dis, b3, out, N);
}

// Round 6
// 428.878 us; speedup vs baseline: 4.2483x; 1.2670x over previous
//
#include <hip/hip_runtime.h>
#include <hip/hip_fp16.h>

// GCN 3->32->32->1, N=100K, E=6.4M (+self loops).
// R5 lessons: k_l2 latency-bound (1 outstanding gather/group, VALU 23%) and
// 72% L2-miss (g 12.8MB > 4MB/XCD L2). R6: (a) g stored fp16 -> 64B rows,
// 6.4MB working set ~= L2; (b) 8-wide unrolled gather, 8 independent
// accumulators -> 8 loads in flight per group; (c) prep+scat2 fused into one
// LDS pass (k_sort); (d) shfl-based scanA. Zero global atomics anywhere.
// norm factored: y = dis*x, g = dis*h1 (fp16), q = dis*p; self-loop per node.

#define BLK 256
#define SB 1024          // first-pass chunks
#define BKT 128          // nodes per bucket
#define MAXNB 1024       // >= NB = ceil(N/BKT) = 782
#define BUFSZ 15360      // bucket sort LDS buffer (mean 8192, ~79 sigma)

// ---- pass 1: per-chunk histogram over dst buckets (LDS, no global atomics)
__global__ void k_hist(const int* __restrict__ dst, int* __restrict__ hist,
                       int E, int chunk, int NB) {
    __shared__ int lh[MAXNB];
    for (int b = threadIdx.x; b < NB; b += blockDim.x) lh[b] = 0;
    __syncthreads();
    int beg = blockIdx.x * chunk, end = min(E, beg + chunk);
    for (int e = beg + threadIdx.x; e < end; e += blockDim.x)
        atomicAdd(&lh[dst[e] >> 7], 1);
    __syncthreads();
    for (int b = threadIdx.x; b < NB; b += blockDim.x)
        hist[(size_t)blockIdx.x * NB + b] = lh[b];
}

// ---- scan A: per bucket, exclusive-scan its SB chunk-counts (shfl-based)
__global__ void k_scanA(int* __restrict__ hist, int* __restrict__ btot, int NB) {
    int b = blockIdx.x, t = threadIdx.x;          // 256 threads, 4 items each
    int base = t * 4;
    int v0 = hist[(size_t)(base + 0) * NB + b];
    int v1 = hist[(size_t)(base + 1) * NB + b];
    int v2 = hist[(size_t)(base + 2) * NB + b];
    int v3 = hist[(size_t)(base + 3) * NB + b];
    int s = v0 + v1 + v2 + v3;
    int lane = t & 63, w = t >> 6;
    int x = s;
#pragma unroll
    for (int off = 1; off < 64; off <<= 1) {
        int u = __shfl_up(x, off, 64);
        if (lane >= off) x += u;
    }
    __shared__ int wsum[4];
    if (lane == 63) wsum[w] = x;
    __syncthreads();
    int woff = 0;
    for (int k = 0; k < 4; k++) woff += (k < w) ? wsum[k] : 0;
    int run = woff + x - s;                       // exclusive prefix for item 0
    hist[(size_t)(base + 0) * NB + b] = run;  run += v0;
    hist[(size_t)(base + 1) * NB + b] = run;  run += v1;
    hist[(size_t)(base + 2) * NB + b] = run;  run += v2;
    hist[(size_t)(base + 3) * NB + b] = run;  run += v3;
    if (t == 255) btot[b] = run;
}

// ---- scan B: exclusive-scan bucket totals -> bucket base offsets
__global__ void k_scanB(const int* __restrict__ btot, int* __restrict__ bbase,
                        int NB, int E) {
    __shared__ int sh[MAXNB];
    int t = threadIdx.x;
    int v = (t < NB) ? btot[t] : 0;
    sh[t] = v;
    __syncthreads();
    for (int off = 1; off < MAXNB; off <<= 1) {
        int u = (t >= off) ? sh[t - off] : 0;
        __syncthreads();
        sh[t] += u;
        __syncthreads();
    }
    if (t < NB) bbase[t] = sh[t] - v;
    if (t == 0) bbase[NB] = E;
}

// ---- pass 2: scatter into bucket regions, LDS cursors (no global atomics)
__global__ void k_scat(const int* __restrict__ src, const int* __restrict__ dst,
                       const int* __restrict__ hist, const int* __restrict__ bbase,
                       unsigned int* __restrict__ packed, int E, int chunk, int NB) {
    __shared__ int base[MAXNB];
    __shared__ int cur[MAXNB];
    for (int b = threadIdx.x; b < NB; b += blockDim.x) {
        base[b] = bbase[b] + hist[(size_t)blockIdx.x * NB + b];
        cur[b] = 0;
    }
    __syncthreads();
    int beg = blockIdx.x * chunk, end = min(E, beg + chunk);
    for (int e = beg + threadIdx.x; e < end; e += blockDim.x) {
        int d = dst[e];
        int b = d >> 7;
        int off = atomicAdd(&cur[b], 1);
        packed[base[b] + off] = (unsigned)src[e] | ((unsigned)(d & 127) << 17);
    }
}

// ---- fused: per-bucket count + scan + dis/y4/rowptr + in-place node sort
__global__ void k_sort(unsigned int* __restrict__ packed, const int* __restrict__ bbase,
                       const float* __restrict__ x, float* __restrict__ dis,
                       float4* __restrict__ y4, int* __restrict__ rowptr, int N, int E) {
    __shared__ unsigned int buf[BUFSZ];
    __shared__ int cnt[BKT];
    __shared__ int sc[BKT];
    __shared__ int cur[BKT];
    int b = blockIdx.x, t = threadIdx.x;
    int beg = bbase[b], end = bbase[b + 1];
    int len = end - beg;
    for (int i = t; i < len; i += blockDim.x) buf[i] = packed[beg + i];
    if (t < BKT) cnt[t] = 0;
    __syncthreads();
    for (int i = t; i < len; i += blockDim.x)
        atomicAdd(&cnt[buf[i] >> 17], 1);
    __syncthreads();
    int v = 0;
    if (t < BKT) { v = cnt[t]; sc[t] = v; }
    __syncthreads();
    for (int off = 1; off < BKT; off <<= 1) {
        int u = 0;
        if (t < BKT && t >= off) u = sc[t - off];
        __syncthreads();
        if (t < BKT) sc[t] += u;
        __syncthreads();
    }
    if (t < BKT) {
        int excl = sc[t] - v;
        cur[t] = excl;
        int gi = b * BKT + t;
        if (gi < N) {
            rowptr[gi] = beg + excl;
            float di = rsqrtf((float)v + 1.0f);      // + self loop
            dis[gi] = di;
            float4 y;
            y.x = di * x[3 * gi + 0];
            y.y = di * x[3 * gi + 1];
            y.z = di * x[3 * gi + 2];
            y.w = 0.0f;
            y4[gi] = y;
        }
    }
    __syncthreads();
    for (int i = t; i < len; i += blockDim.x) {
        unsigned vv = buf[i];
        int pos = atomicAdd(&cur[vv >> 17], 1);      // LDS atomic
        packed[beg + pos] = vv & 0x1FFFF;            // plain src id, node-sorted
    }
    if (b == 0 && t == 0) rowptr[N] = E;
}

// ---- layer 1: node-parallel, 32 lanes/node gather y4 (1.6MB, L2-resident)
__global__ void k_l1(const unsigned int* __restrict__ csr, const int* __restrict__ rowptr,
                     const float4* __restrict__ y4, const float* __restrict__ dis,
                     const float* __restrict__ W1, const float* __restrict__ b1,
                     __half* __restrict__ g, int N) {
    int t = blockIdx.x * blockDim.x + threadIdx.x;
    int i = t >> 5, j = t & 31;
    if (i >= N) return;
    int beg = rowptr[i], end = rowptr[i + 1];
    float ax = 0.f, ay = 0.f, az = 0.f;
    for (int e = beg + j; e < end; e += 32) {
        float4 yv = y4[csr[e]];
        ax += yv.x; ay += yv.y; az += yv.z;
    }
#pragma unroll
    for (int m = 16; m >= 1; m >>= 1) {
        ax += __shfl_xor(ax, m, 32);
        ay += __shfl_xor(ay, m, 32);
        az += __shfl_xor(az, m, 32);
    }
    float di = dis[i];
    float4 ys = y4[i];                               // self loop (pre-scaled)
    float a0 = di * (ax + ys.x);
    float a1 = di * (ay + ys.y);
    float a2 = di * (az + ys.z);
    float h = b1[j] + a0 * W1[j] + a1 * W1[32 + j] + a2 * W1[64 + j];
    g[(size_t)i * 32 + j] = __float2half(di * fmaxf(h, 0.f));
}

// ---- layer 2 (+L3 projection): 8-wide unrolled fp16 row gathers
__global__ void k_l2(const unsigned int* __restrict__ csr, const int* __restrict__ rowptr,
                     const __half* __restrict__ g, const float* __restrict__ dis,
                     const float* __restrict__ W2, const float* __restrict__ b2,
                     const float* __restrict__ W3, float* __restrict__ q, int N) {
    int t = blockIdx.x * blockDim.x + threadIdx.x;
    int i = t >> 5, j = t & 31;
    if (i >= N) return;
    int beg = rowptr[i], end = rowptr[i + 1];
    float a0 = 0.f, a1 = 0.f, a2 = 0.f, a3 = 0.f;
    float a4 = 0.f, a5 = 0.f, a6 = 0.f, a7 = 0.f;
    for (int k0 = beg; k0 < end; k0 += 32) {
        int e = k0 + j;
        int myedge = (e < end) ? (int)csr[e] : 0;    // coalesced chunk load
        int cnt = min(32, end - k0);
        int t2 = 0;
        for (; t2 + 8 <= cnt; t2 += 8) {             // 8 independent gathers in flight
            int s0 = __shfl(myedge, t2 + 0, 32);
            int s1 = __shfl(myedge, t2 + 1, 32);
            int s2 = __shfl(myedge, t2 + 2, 32);
            int s3 = __shfl(myedge, t2 + 3, 32);
            int s4 = __shfl(myedge, t2 + 4, 32);
            int s5 = __shfl(myedge, t2 + 5, 32);
            int s6 = __shfl(myedge, t2 + 6, 32);
            int s7 = __shfl(myedge, t2 + 7, 32);
            a0 += __half2float(g[(size_t)s0 * 32 + j]);
            a1 += __half2float(g[(size_t)s1 * 32 + j]);
            a2 += __half2float(g[(size_t)s2 * 32 + j]);
            a3 += __half2float(g[(size_t)s3 * 32 + j]);
            a4 += __half2float(g[(size_t)s4 * 32 + j]);
            a5 += __half2float(g[(size_t)s5 * 32 + j]);
            a6 += __half2float(g[(size_t)s6 * 32 + j]);
            a7 += __half2float(g[(size_t)s7 * 32 + j]);
        }
        for (; t2 < cnt; t2++) {
            int s = __shfl(myedge, t2, 32);
            a0 += __half2float(g[(size_t)s * 32 + j]);
        }
    }
    float acc = ((a0 + a1) + (a2 + a3)) + ((a4 + a5) + (a6 + a7));
    float di = dis[i];
    float a = di * (acc + __half2float(g[(size_t)i * 32 + j]));   // + self loop
    float o = b2[j];
#pragma unroll
    for (int k = 0; k < 32; k++)
        o += __shfl(a, k, 32) * W2[k * 32 + j];
    float h2 = fmaxf(o, 0.f);
    float c = h2 * W3[j];
#pragma unroll
    for (int m = 16; m >= 1; m >>= 1)
        c += __shfl_xor(c, m, 32);
    if (j == 0) q[i] = di * c;                       // q = dis * p
}

// ---- layer 3: node-parallel scalar q gathers (q 400KB, L2-resident)
__global__ void k_l3(const unsigned int* __restrict__ csr, const int* __restrict__ rowptr,
                     const float* __restrict__ q, const float* __restrict__ dis,
                     const float* __restrict__ b3, float* __restrict__ out, int N) {
    int t = blockIdx.x * blockDim.x + threadIdx.x;
    int i = t >> 5, j = t & 31;
    if (i >= N) return;
    int beg = rowptr[i], end = rowptr[i + 1];
    float acc = 0.f;
    for (int e = beg + j; e < end; e += 32)
        acc += q[csr[e]];
#pragma unroll
    for (int m = 16; m >= 1; m >>= 1)
        acc += __shfl_xor(acc, m, 32);
    if (j == 0) out[i] = dis[i] * (acc + q[i]) + b3[0];
}

extern "C" void kernel_launch(void* const* d_in, const int* in_sizes, int n_in,
                              void* d_out, int out_size, void* d_ws, size_t ws_size,
                              hipStream_t stream) {
    const float* x  = (const float*)d_in[0];
    const int*   ei = (const int*)d_in[1];
    const float* W1 = (const float*)d_in[2];
    const float* b1 = (const float*)d_in[3];
    const float* W2 = (const float*)d_in[4];
    const float* b2 = (const float*)d_in[5];
    const float* W3 = (const float*)d_in[6];
    const float* b3 = (const float*)d_in[7];
    float* out = (float*)d_out;

    int N = in_sizes[0] / 3;
    int E = in_sizes[1] / 2;
    const int* src = ei;
    const int* dst = ei + E;
    int NB = (N + BKT - 1) / BKT;                    // 782
    int chunk = (E + SB - 1) / SB;

    // workspace (all init done in-kernel; no memset needed)
    char* w = (char*)d_ws;
    int*   hist   = (int*)w;       w += (size_t)SB * NB * 4;        // 3.2 MB
    int*   btot   = (int*)w;       w += (size_t)MAXNB * 4;
    int*   bbase  = (int*)w;       w += (size_t)(MAXNB + 1) * 4;
    int*   rowptr = (int*)w;       w += (size_t)(N + 1) * 4;
    float* dis    = (float*)w;     w += (size_t)N * 4;
    float* y4     = (float*)w;     w += (size_t)N * 16;
    __half* g     = (__half*)w;    w += (size_t)N * 32 * 2;          // 6.4 MB fp16
    float* q      = (float*)w;     w += (size_t)N * 4;
    unsigned int* packed = (unsigned int*)w;  w += (size_t)E * 4;    // 25.6 MB

    k_hist <<<SB, BLK, 0, stream>>>(dst, hist, E, chunk, NB);
    k_scanA<<<NB, BLK, 0, stream>>>(hist, btot, NB);
    k_scanB<<<1, MAXNB, 0, stream>>>(btot, bbase, NB, E);
    k_scat <<<SB, BLK, 0, stream>>>(src, dst, hist, bbase, packed, E, chunk, NB);
    k_sort <<<NB, BLK, 0, stream>>>(packed, bbase, x, dis, (float4*)y4, rowptr, N, E);

    long long tn = (long long)N * 32;
    unsigned gn = (unsigned)((tn + BLK - 1) / BLK);
    k_l1<<<gn, BLK, 0, stream>>>(packed, rowptr, (const float4*)y4, dis, W1, b1, g, N);
    k_l2<<<gn, BLK, 0, stream>>>(packed, rowptr, g, dis, W2, b2, W3, q, N);
    k_l3<<<gn, BLK, 0, stream>>>(packed, rowptr, q, dis, b3, out, N);
}